// Round 9
// baseline (22.644 us; speedup 1.0000x reference)
//
#include <hip/hip_runtime.h>
#include <math.h>

constexpr int IMG = 224;
constexpr int Bb  = 16;
constexpr int Vv  = 8;
constexpr int Nn  = 8192;
constexpr int Mm  = 1024;
constexpr int G   = 32;                 // bins per axis
constexpr float Hh = 1.0f / 32.0f;      // cell size, normalized coords

// ws layout: entries float4[Bb][Mm] (256 KiB) | starts ushort[Bb][1040]

// ---------- Kernel A: bin candidates into a 32x32 grid --------------------
__global__ __launch_bounds__(256) void prep_kernel(
    const float* __restrict__ bounds, const int* __restrict__ view_p,
    float4* __restrict__ ws_e, unsigned short* __restrict__ ws_s)
{
    const int view = *view_p;
    const int b = blockIdx.x;
    const int t = threadIdx.x;
    const int lane = t & 63;
    const int w = t >> 6;
    __shared__ int s_cnt[1024];           // counts, then reused as cursors
    __shared__ int s_wtot[4];
    #pragma unroll
    for (int u = 0; u < 4; ++u) s_cnt[t + 256 * u] = 0;
    __syncthreads();

    const float* bnd = bounds + (size_t)(b * Vv + view) * Mm * 2;
    float bdx[4], bdy[4];
    int cell[4];
    #pragma unroll
    for (int u = 0; u < 4; ++u) {
        int j = t + 256 * u;
        float2 bxy = reinterpret_cast<const float2*>(bnd)[j];
        bdx[u] = bxy.x / (float)IMG;      // exact IEEE div, matches ref
        bdy[u] = bxy.y / (float)IMG;
        int cx = min(G - 1, max(0, (int)(bdx[u] * (float)G)));
        int cy = min(G - 1, max(0, (int)(bdy[u] * (float)G)));
        cell[u] = cy * G + cx;
        atomicAdd(&s_cnt[cell[u]], 1);
    }
    __syncthreads();

    // prefix sum over 1024 cells: 4 serial/thread + wave shfl-scan + fixup
    int c0 = s_cnt[4 * t], c1 = s_cnt[4 * t + 1];
    int c2 = s_cnt[4 * t + 2], c3 = s_cnt[4 * t + 3];
    int psum = c0 + c1 + c2 + c3;
    int incl = psum;
    #pragma unroll
    for (int off = 1; off < 64; off <<= 1) {
        int v = __shfl_up(incl, off);
        if (lane >= off) incl += v;
    }
    if (lane == 63) s_wtot[w] = incl;
    __syncthreads();
    int basew = 0;
    for (int ww = 0; ww < w; ++ww) basew += s_wtot[ww];
    int base = basew + incl - psum;       // exclusive over cell group 4t..
    int st0 = base, st1 = base + c0, st2 = base + c0 + c1, st3 = base + c0 + c1 + c2;
    unsigned short* wss = ws_s + b * 1040;
    wss[4 * t]     = (unsigned short)st0;
    wss[4 * t + 1] = (unsigned short)st1;
    wss[4 * t + 2] = (unsigned short)st2;
    wss[4 * t + 3] = (unsigned short)st3;
    if (t == 0) wss[1024] = (unsigned short)Mm;
    s_cnt[4 * t] = st0; s_cnt[4 * t + 1] = st1;
    s_cnt[4 * t + 2] = st2; s_cnt[4 * t + 3] = st3;
    __syncthreads();

    // scatter packed entries (intra-cell order atomic-arbitrary; lex (d2,j)
    // reduction makes the final result order-invariant)
    #pragma unroll
    for (int u = 0; u < 4; ++u) {
        int j = t + 256 * u;
        int pos = atomicAdd(&s_cnt[cell[u]], 1);
        float nrm = __fadd_rn(__fmul_rn(bdx[u], bdx[u]), __fmul_rn(bdy[u], bdy[u]));
        ws_e[(size_t)b * Mm + pos] = make_float4(bdx[u], bdy[u], nrm, __int_as_float(j));
    }
}

// ---------- Kernel B: grid-pruned NN, no LDS, no barriers -----------------
// Block = 256 threads = 64 points x 4 lanes. Candidate table (16 KB/batch)
// and starts (2 KB/batch) are L1/L2-hot (just written by prep) -> read direct.
__global__ __launch_bounds__(256, 8) void calib_kernel(
    const float* __restrict__ pc,         // (B, N, 3)
    const float* __restrict__ mask,       // (B, V, IMG, IMG)
    const float* __restrict__ bounds,     // (B, V, M, 2)
    const float* __restrict__ inv_param,  // (B, V, 4, 4)
    const float* __restrict__ proj_fine,  // (B, V, N, 2)
    const float* __restrict__ proj_finez, // (B, V, N)
    const int*   __restrict__ view_p,
    const float4* __restrict__ ws_e,
    const unsigned short* __restrict__ ws_s,
    float*       __restrict__ out)        // (B, N, 3)
{
    const int view = *view_p;
    const int b = blockIdx.y;
    const int t = threadIdx.x;
    const int s = t & 3;
    const int p = t >> 2;
    const int i = blockIdx.x * 64 + p;

    const float4* we = ws_e + (size_t)b * Mm;
    const unsigned short* wss = ws_s + b * 1040;

    const size_t pf = (size_t)(b * Vv + view) * Nn + i;
    float2 pxy = reinterpret_cast<const float2*>(proj_fine)[pf];

    int i0 = (int)rintf(pxy.x);                 // round half-to-even
    int i1 = (int)rintf((float)IMG - pxy.y);

    // padded-mask probe
    int xi = min(max(i1 + 1, 0), IMG + 1);
    int yi = min(max(i0 + 1, 0), IMG + 1);
    float mval = 0.0f;
    if (xi >= 1 && xi <= IMG && yi >= 1 && yi <= IMG)
        mval = mask[((size_t)(b * Vv + view) * IMG + (xi - 1)) * IMG + (yi - 1)];
    const bool use_back = (mval == 0.0f);

    if (use_back) {
        float ox = (float)i0 / (float)IMG;
        float oy = (float)i1 / (float)IMG;
        float o2 = __fadd_rn(__fmul_rn(ox, ox), __fmul_rn(oy, oy));
        // exact power-of-2 scale; d2 bits identical to prior rounds
        float n2ox = __fmul_rn(-2.0f, ox);
        float n2oy = __fmul_rn(-2.0f, oy);

        int cx = min(G - 1, max(0, (int)(ox * (float)G)));
        int cy = min(G - 1, max(0, (int)(oy * (float)G)));

        float best = INFINITY;
        int   bj   = 0;

        // ---- tier 1: full 5x5 window as 5 contiguous row-ranges ---------
        int x0 = max(cx - 2, 0), x1 = min(cx + 2, G - 1);
        int bases[5], offs[5];
        int T = 0;
        #pragma unroll
        for (int r = 0; r < 5; ++r) {
            int yy = cy - 2 + r;
            int bb = 0, LL = 0;
            if (yy >= 0 && yy < G) {
                int rowb = yy * G;
                int e0 = wss[rowb + x0];
                int e1 = wss[rowb + x1 + 1];
                bb = e0; LL = e1 - e0;
            }
            bases[r] = bb; offs[r] = T; T += LL;
        }
        for (int u = s; u < T; u += 4) {
            int base = bases[0], off = offs[0];
            #pragma unroll
            for (int r = 1; r < 5; ++r) {        // compile-time unrolled -> regs
                bool in = (u >= offs[r]);
                base = in ? bases[r] : base;
                off  = in ? offs[r]  : off;
            }
            float4 cd = we[base + (u - off)];
            float dn = __fadd_rn(__fmul_rn(n2ox, cd.x), __fmul_rn(n2oy, cd.y));
            float d2 = __fadd_rn(__fadd_rn(o2, cd.z), dn);
            int   j  = __float_as_int(cd.w);
            bool better = (d2 < best) || (d2 == best && j < bj);
            best = better ? d2 : best;
            bj   = better ? j  : bj;
        }
        #pragma unroll
        for (int off = 1; off < 4; off <<= 1) {
            float bo = __shfl_xor(best, off);
            int   jo = __shfl_xor(bj, off);
            bool  c  = (bo < best) || (bo == best && jo < bj);
            best = c ? bo : best;
            bj   = c ? jo : bj;
        }

        // ---- tier 2 (P~3e-6): serial ring walker, rings >= 3 ------------
        // unvisited = Chebyshev cell-ring >= 3 => d >= 2h => d2 >= 4h^2-slop
        if (!(best < 4.0f * Hh * Hh - 1e-5f) && s == 0) {
            for (int r = 3; r <= G; ++r) {
                float lim = (float)(r - 1) * Hh;
                if (best < lim * lim - 1e-5f) break;
                int rx0 = max(0, cx - r), rx1 = min(G - 1, cx + r);
                int ry0 = max(0, cy - r), ry1 = min(G - 1, cy + r);
                for (int yy = ry0; yy <= ry1; ++yy) {
                    bool yedge = (yy == cy - r) || (yy == cy + r);
                    for (int xx = rx0; xx <= rx1; ++xx) {
                        if (!yedge && xx != cx - r && xx != cx + r) continue;
                        int c = yy * G + xx;
                        int e0 = wss[c], e1 = wss[c + 1];
                        for (int e = e0; e < e1; ++e) {
                            float4 cd = we[e];
                            float dn = __fadd_rn(__fmul_rn(n2ox, cd.x), __fmul_rn(n2oy, cd.y));
                            float d2 = __fadd_rn(__fadd_rn(o2, cd.z), dn);
                            int   j  = __float_as_int(cd.w);
                            bool better = (d2 < best) || (d2 == best && j < bj);
                            best = better ? d2 : best;
                            bj   = better ? j  : bj;
                        }
                    }
                }
            }
        }

        if (s == 0) {
            // back-projection: [nbx*z, nby*z, z, 1] @ inv_param[:, 0:3]
            const float* bnd = bounds + (size_t)(b * Vv + view) * Mm * 2;
            float nbx = bnd[2 * bj];
            float nby = bnd[2 * bj + 1];
            float z   = proj_finez[pf];
            const float* ip = inv_param + (size_t)(b * Vv + view) * 16;
            float h0 = nbx * z, h1 = nby * z;
            float r0 = h0 * ip[0] + h1 * ip[4] + z * ip[8]  + ip[12];
            float r1 = h0 * ip[1] + h1 * ip[5] + z * ip[9]  + ip[13];
            float r2 = h0 * ip[2] + h1 * ip[6] + z * ip[10] + ip[14];
            const size_t ob = ((size_t)b * Nn + i) * 3;
            out[ob]     = r0;
            out[ob + 1] = r1;
            out[ob + 2] = r2;
        }
    } else if (s == 0) {
        const size_t ob = ((size_t)b * Nn + i) * 3;
        out[ob]     = pc[ob];
        out[ob + 1] = pc[ob + 1];
        out[ob + 2] = pc[ob + 2];
    }
}

// ---------- Fallback: full scan (known-correct), if ws too small ----------
__global__ __launch_bounds__(256) void calib_fallback(
    const float* __restrict__ pc, const float* __restrict__ mask,
    const float* __restrict__ bounds, const float* __restrict__ inv_param,
    const float* __restrict__ proj_fine, const float* __restrict__ proj_finez,
    const int* __restrict__ view_p, float* __restrict__ out)
{
    const int view = *view_p;
    const int b = blockIdx.y;
    const int s = threadIdx.x & 3;
    const int p_local = threadIdx.x >> 2;
    const int i = blockIdx.x * 64 + p_local;

    __shared__ float4 s_bd[Mm];
    const float* bnd = bounds + (size_t)(b * Vv + view) * Mm * 2;
    for (int j = threadIdx.x; j < Mm; j += 256) {
        float2 bxy = reinterpret_cast<const float2*>(bnd)[j];
        float bdx = bxy.x / (float)IMG;
        float bdy = bxy.y / (float)IMG;
        float nrm = __fadd_rn(__fmul_rn(bdx, bdx), __fmul_rn(bdy, bdy));
        s_bd[j] = make_float4(bdx, bdy, nrm, 0.0f);
    }
    __syncthreads();

    const size_t pf = (size_t)(b * Vv + view) * Nn + i;
    float2 pxy = reinterpret_cast<const float2*>(proj_fine)[pf];
    int i0 = (int)rintf(pxy.x);
    int i1 = (int)rintf((float)IMG - pxy.y);
    float ox = (float)i0 / (float)IMG;
    float oy = (float)i1 / (float)IMG;
    float o2 = __fadd_rn(__fmul_rn(ox, ox), __fmul_rn(oy, oy));
    float n2ox = __fmul_rn(-2.0f, ox);
    float n2oy = __fmul_rn(-2.0f, oy);

    float best = INFINITY;
    int bj = 0;
    const float4* sp = s_bd + s;
    #pragma unroll 4
    for (int q = 0; q < Mm / 4; ++q) {
        float4 bd = sp[4 * q];
        int j = 4 * q + s;
        float dn = __fadd_rn(__fmul_rn(n2ox, bd.x), __fmul_rn(n2oy, bd.y));
        float d2 = __fadd_rn(__fadd_rn(o2, bd.z), dn);
        bool c = d2 < best;
        bj = c ? j : bj;
        best = fminf(best, d2);
    }
    #pragma unroll
    for (int off = 1; off < 4; off <<= 1) {
        float bo = __shfl_xor(best, off);
        int   jo = __shfl_xor(bj, off);
        bool  c  = (bo < best) || (bo == best && jo < bj);
        best = c ? bo : best;
        bj   = c ? jo : bj;
    }
    if (s == 0) {
        int xi = min(max(i1 + 1, 0), IMG + 1);
        int yi = min(max(i0 + 1, 0), IMG + 1);
        float mval = 0.0f;
        if (xi >= 1 && xi <= IMG && yi >= 1 && yi <= IMG)
            mval = mask[((size_t)(b * Vv + view) * IMG + (xi - 1)) * IMG + (yi - 1)];
        const bool use_back = (mval == 0.0f);
        float nbx = bnd[2 * bj];
        float nby = bnd[2 * bj + 1];
        float z   = proj_finez[pf];
        const float* ip = inv_param + (size_t)(b * Vv + view) * 16;
        float h0 = nbx * z, h1 = nby * z;
        float r0 = h0 * ip[0] + h1 * ip[4] + z * ip[8]  + ip[12];
        float r1 = h0 * ip[1] + h1 * ip[5] + z * ip[9]  + ip[13];
        float r2 = h0 * ip[2] + h1 * ip[6] + z * ip[10] + ip[14];
        const size_t ob = ((size_t)b * Nn + i) * 3;
        float c0 = pc[ob], c1 = pc[ob + 1], c2 = pc[ob + 2];
        out[ob]     = use_back ? r0 : c0;
        out[ob + 1] = use_back ? r1 : c1;
        out[ob + 2] = use_back ? r2 : c2;
    }
}

extern "C" void kernel_launch(void* const* d_in, const int* in_sizes, int n_in,
                              void* d_out, int out_size, void* d_ws, size_t ws_size,
                              hipStream_t stream) {
    const float* pc         = (const float*)d_in[0];
    const float* mask       = (const float*)d_in[1];
    const float* bounds     = (const float*)d_in[2];
    const float* inv_param  = (const float*)d_in[3];
    const float* proj_fine  = (const float*)d_in[4];
    const float* proj_finez = (const float*)d_in[5];
    const int*   view_p     = (const int*)d_in[6];
    float* out = (float*)d_out;

    const size_t ws_need = (size_t)Bb * Mm * sizeof(float4)
                         + (size_t)Bb * 1040 * sizeof(unsigned short);
    if (ws_size >= ws_need) {
        float4* ws_e = (float4*)d_ws;
        unsigned short* ws_s =
            (unsigned short*)((char*)d_ws + (size_t)Bb * Mm * sizeof(float4));
        prep_kernel<<<dim3(Bb), 256, 0, stream>>>(bounds, view_p, ws_e, ws_s);
        dim3 grid(Nn / 64, Bb);
        calib_kernel<<<grid, 256, 0, stream>>>(pc, mask, bounds, inv_param,
                                               proj_fine, proj_finez, view_p,
                                               ws_e, ws_s, out);
    } else {
        dim3 grid(Nn / 64, Bb);
        calib_fallback<<<grid, 256, 0, stream>>>(pc, mask, bounds, inv_param,
                                                 proj_fine, proj_finez, view_p,
                                                 out);
    }
}

// Round 10
// 19.054 us; speedup vs baseline: 1.1884x; 1.1884x over previous
//
#include <hip/hip_runtime.h>
#include <math.h>

constexpr int IMG = 224;
constexpr int Bb  = 16;
constexpr int Vv  = 8;
constexpr int Nn  = 8192;
constexpr int Mm  = 1024;
constexpr int G   = 32;                 // bins per axis
constexpr float Hh = 1.0f / 32.0f;      // cell size, normalized coords

// Single fused kernel: per-block binning of its batch (redundant across the
// 32 chunks of a batch, but ~1 us total) + per-thread grid-pruned NN search.
// No workspace, no second launch, no cross-block dependency.
__global__ __launch_bounds__(256) void calib_kernel(
    const float* __restrict__ pc,         // (B, N, 3)
    const float* __restrict__ mask,       // (B, V, IMG, IMG)
    const float* __restrict__ bounds,     // (B, V, M, 2)
    const float* __restrict__ inv_param,  // (B, V, 4, 4)
    const float* __restrict__ proj_fine,  // (B, V, N, 2)
    const float* __restrict__ proj_finez, // (B, V, N)
    const int*   __restrict__ view_p,
    float*       __restrict__ out)        // (B, N, 3)
{
    const int view = *view_p;
    const int b = blockIdx.y;
    const int t = threadIdx.x;
    const int lane = t & 63;
    const int w = t >> 6;

    __shared__ float4 s_e[Mm];            // packed (bdx, bdy, |bd|^2, j)
    __shared__ int s_start[1025];         // cell -> range start
    __shared__ int s_cnt[1024];           // counts, then cursors
    __shared__ int s_wtot[4];

    // ---------------- phase 1: bin this batch's candidates ----------------
    #pragma unroll
    for (int u = 0; u < 4; ++u) s_cnt[t + 256 * u] = 0;
    __syncthreads();

    const float* bnd = bounds + (size_t)(b * Vv + view) * Mm * 2;
    float bdx[4], bdy[4];
    int cell[4];
    #pragma unroll
    for (int u = 0; u < 4; ++u) {
        int j = t + 256 * u;
        float2 bxy = reinterpret_cast<const float2*>(bnd)[j];
        bdx[u] = bxy.x / (float)IMG;      // exact IEEE div, matches ref
        bdy[u] = bxy.y / (float)IMG;
        int cx = min(G - 1, max(0, (int)(bdx[u] * (float)G)));
        int cy = min(G - 1, max(0, (int)(bdy[u] * (float)G)));
        cell[u] = cy * G + cx;
        atomicAdd(&s_cnt[cell[u]], 1);
    }
    __syncthreads();

    // prefix sum over 1024 cells: 4 serial/thread + wave shfl-scan + fixup
    int c0 = s_cnt[4 * t], c1 = s_cnt[4 * t + 1];
    int c2 = s_cnt[4 * t + 2], c3 = s_cnt[4 * t + 3];
    int psum = c0 + c1 + c2 + c3;
    int incl = psum;
    #pragma unroll
    for (int off = 1; off < 64; off <<= 1) {
        int v = __shfl_up(incl, off);
        if (lane >= off) incl += v;
    }
    if (lane == 63) s_wtot[w] = incl;
    __syncthreads();
    int basew = 0;
    for (int ww = 0; ww < w; ++ww) basew += s_wtot[ww];
    int base = basew + incl - psum;       // exclusive start of cell 4t
    int st0 = base, st1 = base + c0, st2 = base + c0 + c1, st3 = base + c0 + c1 + c2;
    s_start[4 * t] = st0; s_start[4 * t + 1] = st1;
    s_start[4 * t + 2] = st2; s_start[4 * t + 3] = st3;
    if (t == 0) s_start[1024] = Mm;
    s_cnt[4 * t] = st0; s_cnt[4 * t + 1] = st1;
    s_cnt[4 * t + 2] = st2; s_cnt[4 * t + 3] = st3;
    __syncthreads();

    // scatter (intra-cell order atomic-arbitrary; lex (d2,j) reduction makes
    // the final result order-invariant => deterministic output)
    #pragma unroll
    for (int u = 0; u < 4; ++u) {
        int j = t + 256 * u;
        int pos = atomicAdd(&s_cnt[cell[u]], 1);
        float nrm = __fadd_rn(__fmul_rn(bdx[u], bdx[u]), __fmul_rn(bdy[u], bdy[u]));
        s_e[pos] = make_float4(bdx[u], bdy[u], nrm, __int_as_float(j));
    }
    __syncthreads();

    // ---------------- phase 2: one thread = one point ----------------------
    const int i = blockIdx.x * 256 + t;
    const size_t pf = (size_t)(b * Vv + view) * Nn + i;
    float2 pxy = reinterpret_cast<const float2*>(proj_fine)[pf];

    int i0 = (int)rintf(pxy.x);                 // round half-to-even
    int i1 = (int)rintf((float)IMG - pxy.y);

    // padded-mask probe
    int xi = min(max(i1 + 1, 0), IMG + 1);
    int yi = min(max(i0 + 1, 0), IMG + 1);
    float mval = 0.0f;
    if (xi >= 1 && xi <= IMG && yi >= 1 && yi <= IMG)
        mval = mask[((size_t)(b * Vv + view) * IMG + (xi - 1)) * IMG + (yi - 1)];
    const bool use_back = (mval == 0.0f);

    const size_t ob = ((size_t)b * Nn + i) * 3;
    if (use_back) {
        float ox = (float)i0 / (float)IMG;
        float oy = (float)i1 / (float)IMG;
        float o2 = __fadd_rn(__fmul_rn(ox, ox), __fmul_rn(oy, oy));
        // exact power-of-2 scale; d2 bits identical to prior rounds
        float n2ox = __fmul_rn(-2.0f, ox);
        float n2oy = __fmul_rn(-2.0f, oy);

        int cx = min(G - 1, max(0, (int)(ox * (float)G)));
        int cy = min(G - 1, max(0, (int)(oy * (float)G)));

        float best = INFINITY;
        int   bj   = 0;

        // tier 1: full 5x5 window, serial per thread (visit order irrelevant)
        int x0 = max(cx - 2, 0), x1 = min(cx + 2, G - 1);
        int y0 = max(cy - 2, 0), y1 = min(cy + 2, G - 1);
        for (int yy = y0; yy <= y1; ++yy) {
            int rowb = yy * G;
            int e0 = s_start[rowb + x0];
            int e1 = s_start[rowb + x1 + 1];
            for (int e = e0; e < e1; ++e) {
                float4 cd = s_e[e];
                float dn = __fadd_rn(__fmul_rn(n2ox, cd.x), __fmul_rn(n2oy, cd.y));
                float d2 = __fadd_rn(__fadd_rn(o2, cd.z), dn);
                int   j  = __float_as_int(cd.w);
                bool better = (d2 < best) || (d2 == best && j < bj);
                best = better ? d2 : best;
                bj   = better ? j  : bj;
            }
        }

        // tier 2 (P~3e-6): serial ring walker, rings >= 3.
        // unvisited = Chebyshev cell-ring >= 3 => d >= 2h => d2 >= 4h^2-slop
        if (!(best < 4.0f * Hh * Hh - 1e-5f)) {
            for (int r = 3; r <= G; ++r) {
                float lim = (float)(r - 1) * Hh;
                if (best < lim * lim - 1e-5f) break;
                int rx0 = max(0, cx - r), rx1 = min(G - 1, cx + r);
                int ry0 = max(0, cy - r), ry1 = min(G - 1, cy + r);
                for (int yy = ry0; yy <= ry1; ++yy) {
                    bool yedge = (yy == cy - r) || (yy == cy + r);
                    for (int xx = rx0; xx <= rx1; ++xx) {
                        if (!yedge && xx != cx - r && xx != cx + r) continue;
                        int c = yy * G + xx;
                        int e0 = s_start[c], e1 = s_start[c + 1];
                        for (int e = e0; e < e1; ++e) {
                            float4 cd = s_e[e];
                            float dn = __fadd_rn(__fmul_rn(n2ox, cd.x), __fmul_rn(n2oy, cd.y));
                            float d2 = __fadd_rn(__fadd_rn(o2, cd.z), dn);
                            int   j  = __float_as_int(cd.w);
                            bool better = (d2 < best) || (d2 == best && j < bj);
                            best = better ? d2 : best;
                            bj   = better ? j  : bj;
                        }
                    }
                }
            }
        }

        // back-projection: [nbx*z, nby*z, z, 1] @ inv_param[b, view][:, 0:3]
        float nbx = bnd[2 * bj];
        float nby = bnd[2 * bj + 1];
        float z   = proj_finez[pf];
        const float* ip = inv_param + (size_t)(b * Vv + view) * 16;
        float h0 = nbx * z, h1 = nby * z;
        float r0 = h0 * ip[0] + h1 * ip[4] + z * ip[8]  + ip[12];
        float r1 = h0 * ip[1] + h1 * ip[5] + z * ip[9]  + ip[13];
        float r2 = h0 * ip[2] + h1 * ip[6] + z * ip[10] + ip[14];
        out[ob]     = r0;
        out[ob + 1] = r1;
        out[ob + 2] = r2;
    } else {
        out[ob]     = pc[ob];
        out[ob + 1] = pc[ob + 1];
        out[ob + 2] = pc[ob + 2];
    }
}

extern "C" void kernel_launch(void* const* d_in, const int* in_sizes, int n_in,
                              void* d_out, int out_size, void* d_ws, size_t ws_size,
                              hipStream_t stream) {
    const float* pc         = (const float*)d_in[0];
    const float* mask       = (const float*)d_in[1];
    const float* bounds     = (const float*)d_in[2];
    const float* inv_param  = (const float*)d_in[3];
    const float* proj_fine  = (const float*)d_in[4];
    const float* proj_finez = (const float*)d_in[5];
    const int*   view_p     = (const int*)d_in[6];
    float* out = (float*)d_out;

    dim3 grid(Nn / 256, Bb);              // 512 blocks, one launch, no ws
    calib_kernel<<<grid, 256, 0, stream>>>(pc, mask, bounds, inv_param,
                                           proj_fine, proj_finez, view_p, out);
}